// Round 2
// baseline (148.335 us; speedup 1.0000x reference)
//
#include <hip/hip_runtime.h>

#define N_TOTAL (8 * 128 * 128 * 128)   // 16,777,216 elements
#define N_VEC4  (N_TOTAL / 4)           // 4,194,304 float4
#define BLOCKS  2048
#define THREADS 256
#define ITERS   (N_VEC4 / (BLOCKS * THREADS))   // = 8, exact

__device__ __forceinline__ float svl_elem(float x, float t) {
    // BCEWithLogits (stable): max(x,0) - x*t + log1p(exp(-|x|))
    float loss = fmaxf(x, 0.0f) - x * t + __logf(1.0f + __expf(-fabsf(x)));
    // sigmoid(x) > 0.5  <=>  x > 0 ; weight = (pred XOR tgt) ? 1.5 : 1.0
    bool pred = x > 0.0f;
    bool tgt  = t > 0.5f;
    float w = (pred != tgt) ? 1.5f : 1.0f;
    return loss * w;
}

__global__ __launch_bounds__(THREADS) void svl_partial_kernel(
        const float4* __restrict__ yp, const float4* __restrict__ yt,
        float* __restrict__ partial) {
    int base = blockIdx.x * THREADS + threadIdx.x;
    const int stride = BLOCKS * THREADS;

    // Batch ALL loads first — 16 independent 16B loads in flight per lane.
    float4 xs[ITERS], ts[ITERS];
    #pragma unroll
    for (int k = 0; k < ITERS; ++k) {
        int i = base + k * stride;      // wave-coalesced at every k
        xs[k] = yp[i];
        ts[k] = yt[i];
    }

    float acc = 0.0f;
    #pragma unroll
    for (int k = 0; k < ITERS; ++k) {
        acc += svl_elem(xs[k].x, ts[k].x);
        acc += svl_elem(xs[k].y, ts[k].y);
        acc += svl_elem(xs[k].z, ts[k].z);
        acc += svl_elem(xs[k].w, ts[k].w);
    }

    // wave-64 shuffle reduction
    #pragma unroll
    for (int off = 32; off > 0; off >>= 1)
        acc += __shfl_down(acc, off, 64);

    __shared__ float smem[THREADS / 64];
    int lane = threadIdx.x & 63;
    int wave = threadIdx.x >> 6;
    if (lane == 0) smem[wave] = acc;
    __syncthreads();

    if (threadIdx.x == 0) {
        float s = 0.0f;
        #pragma unroll
        for (int w = 0; w < THREADS / 64; ++w) s += smem[w];
        partial[blockIdx.x] = s;
    }
}

__global__ __launch_bounds__(THREADS) void svl_final_kernel(
        const float* __restrict__ partial, float* __restrict__ out) {
    float acc = 0.0f;
    for (int i = threadIdx.x; i < BLOCKS; i += THREADS)
        acc += partial[i];

    #pragma unroll
    for (int off = 32; off > 0; off >>= 1)
        acc += __shfl_down(acc, off, 64);

    __shared__ float smem[THREADS / 64];
    int lane = threadIdx.x & 63;
    int wave = threadIdx.x >> 6;
    if (lane == 0) smem[wave] = acc;
    __syncthreads();

    if (threadIdx.x == 0) {
        float s = 0.0f;
        #pragma unroll
        for (int w = 0; w < THREADS / 64; ++w) s += smem[w];
        out[0] = s * (1.0f / (float)N_TOTAL);
    }
}

extern "C" void kernel_launch(void* const* d_in, const int* in_sizes, int n_in,
                              void* d_out, int out_size, void* d_ws, size_t ws_size,
                              hipStream_t stream) {
    const float4* yp = (const float4*)d_in[0];
    const float4* yt = (const float4*)d_in[1];
    float* out = (float*)d_out;
    float* partial = (float*)d_ws;   // BLOCKS floats = 8 KiB scratch

    svl_partial_kernel<<<BLOCKS, THREADS, 0, stream>>>(yp, yt, partial);
    svl_final_kernel<<<1, THREADS, 0, stream>>>(partial, out);
}

// Round 3
// 142.108 us; speedup vs baseline: 1.0438x; 1.0438x over previous
//
#include <hip/hip_runtime.h>

#define N_TOTAL (8 * 128 * 128 * 128)   // 16,777,216 elements
#define N_VEC4  (N_TOTAL / 4)           // 4,194,304 float4
#define BLOCKS  2048
#define THREADS 256
#define ITERS   (N_VEC4 / (BLOCKS * THREADS))   // = 8, exact

typedef float v4f __attribute__((ext_vector_type(4)));

__device__ __forceinline__ float svl_elem(float x, float t) {
    // BCEWithLogits (stable): max(x,0) - x*t + log1p(exp(-|x|))
    float loss = fmaxf(x, 0.0f) - x * t + __logf(1.0f + __expf(-fabsf(x)));
    // sigmoid(x) > 0.5  <=>  x > 0 ; weight = (pred XOR tgt) ? 1.5 : 1.0
    bool pred = x > 0.0f;
    bool tgt  = t > 0.5f;
    float w = (pred != tgt) ? 1.5f : 1.0f;
    return loss * w;
}

__global__ __launch_bounds__(THREADS, 4) void svl_partial_kernel(
        const v4f* __restrict__ yp, const v4f* __restrict__ yt,
        float* __restrict__ partial) {
    int base = blockIdx.x * THREADS + threadIdx.x;
    const int stride = BLOCKS * THREADS;

    // Issue ALL 16 nontemporal loads before any compute — no L2 allocation
    // churn for stream-once data, and real MLP (256 B in flight per lane).
    v4f xs[ITERS], ts[ITERS];
    #pragma unroll
    for (int k = 0; k < ITERS; ++k)
        xs[k] = __builtin_nontemporal_load(yp + base + k * stride);
    #pragma unroll
    for (int k = 0; k < ITERS; ++k)
        ts[k] = __builtin_nontemporal_load(yt + base + k * stride);

    float acc = 0.0f;
    #pragma unroll
    for (int k = 0; k < ITERS; ++k) {
        acc += svl_elem(xs[k].x, ts[k].x);
        acc += svl_elem(xs[k].y, ts[k].y);
        acc += svl_elem(xs[k].z, ts[k].z);
        acc += svl_elem(xs[k].w, ts[k].w);
    }

    // wave-64 shuffle reduction
    #pragma unroll
    for (int off = 32; off > 0; off >>= 1)
        acc += __shfl_down(acc, off, 64);

    __shared__ float smem[THREADS / 64];
    int lane = threadIdx.x & 63;
    int wave = threadIdx.x >> 6;
    if (lane == 0) smem[wave] = acc;
    __syncthreads();

    if (threadIdx.x == 0) {
        float s = 0.0f;
        #pragma unroll
        for (int w = 0; w < THREADS / 64; ++w) s += smem[w];
        partial[blockIdx.x] = s;
    }
}

__global__ __launch_bounds__(THREADS) void svl_final_kernel(
        const float* __restrict__ partial, float* __restrict__ out) {
    float acc = 0.0f;
    for (int i = threadIdx.x; i < BLOCKS; i += THREADS)
        acc += partial[i];

    #pragma unroll
    for (int off = 32; off > 0; off >>= 1)
        acc += __shfl_down(acc, off, 64);

    __shared__ float smem[THREADS / 64];
    int lane = threadIdx.x & 63;
    int wave = threadIdx.x >> 6;
    if (lane == 0) smem[wave] = acc;
    __syncthreads();

    if (threadIdx.x == 0) {
        float s = 0.0f;
        #pragma unroll
        for (int w = 0; w < THREADS / 64; ++w) s += smem[w];
        out[0] = s * (1.0f / (float)N_TOTAL);
    }
}

extern "C" void kernel_launch(void* const* d_in, const int* in_sizes, int n_in,
                              void* d_out, int out_size, void* d_ws, size_t ws_size,
                              hipStream_t stream) {
    const v4f* yp = (const v4f*)d_in[0];
    const v4f* yt = (const v4f*)d_in[1];
    float* out = (float*)d_out;
    float* partial = (float*)d_ws;   // BLOCKS floats = 8 KiB scratch

    svl_partial_kernel<<<BLOCKS, THREADS, 0, stream>>>(yp, yt, partial);
    svl_final_kernel<<<1, THREADS, 0, stream>>>(partial, out);
}